// Round 7
// baseline (137.344 us; speedup 1.0000x reference)
//
#include <hip/hip_runtime.h>
#include <hip/hip_bf16.h>

#define IN_F   128
#define OUT_F  64
#define NG 384              // persistent GEMM blocks
#define NC 128              // edge-count blocks (concurrent); NG+NC = 512 = 2/CU
#define TSTRIDE 136         // W^T LDS stride (ushorts)
#define OSTRIDE 136         // output-stage LDS stride (ushorts, 16B-aligned rows)

typedef __attribute__((ext_vector_type(8))) short short8;   // 8 bf16
typedef __attribute__((ext_vector_type(4))) float floatx4;  // MFMA accumulator

__device__ inline unsigned short f32_to_bf16_rne(float f) {
    unsigned int u = __float_as_uint(f);
    unsigned int r = (u + 0x7FFFu + ((u >> 16) & 1u)) >> 16;
    return (unsigned short)r;
}
__device__ inline float bf16_to_f32(unsigned short u) {
    return __uint_as_float((unsigned int)u << 16);
}

// ---------------------------------------------------------------------------
// K1 (fused): blocks [0,NG) = persistent MFMA GEMM h = x@W (bf16 h out);
// blocks [NG,NG+NC) = count_edges. Co-resident (2 blocks/CU).
// GEMM structure: NO LDS in the K-loop. W-fragments live in 64 VGPRs
// (loaded from LDS once); A-fragments loaded directly from global (each
// lane loads its own 4x32B); explicit 2-deep tile pipeline (xa/xb).
// Output: per-wave LDS transpose -> 2x16B contiguous stores per lane
// (full-sector coverage; kills the 2x write amplification seen in r6).
// ---------------------------------------------------------------------------
__global__ __launch_bounds__(256) void gemm_count(const float* __restrict__ x,
                                                  const float* __restrict__ W,
                                                  unsigned short* __restrict__ h,
                                                  int nTiles,
                                                  const int* __restrict__ edst,
                                                  int* __restrict__ counts,
                                                  int n_edges) {
    __shared__ unsigned short Wt[64 * TSTRIDE];      // 17.4 KB
    __shared__ unsigned short ot[4][16 * OSTRIDE];   // 17.4 KB (per-wave strips)

    const int tid = threadIdx.x;

    if (blockIdx.x >= NG) {
        // --- count role ---
        const int stride = NC * 256;
        for (int e = (blockIdx.x - NG) * 256 + tid; e < n_edges; e += stride)
            atomicAdd(&counts[edst[e]], 1);
        return;
    }

    // --- GEMM role ---
    const int lane = tid & 63;
    const int wave = tid >> 6;          // 0..3 -> rows [16*wave, 16*wave+16)
    const int lrow = lane & 15;
    const int lkg  = lane >> 4;         // k-group; k offset = 8*lkg

    // One-time: W (128x64 f32) -> Wt[col][k] bf16 in LDS.
    #pragma unroll
    for (int i = 0; i < 32; ++i) {
        const int idx = tid + i * 256;          // 0..8191
        Wt[(idx & 63) * TSTRIDE + (idx >> 6)] = f32_to_bf16_rne(W[idx]);
    }
    __syncthreads();

    // Hoist all 16 B-fragments into registers (read LDS exactly once).
    // B-frag (m89 layout): element j = W[kbase + 8*lkg + j][16*t + lrow].
    short8 bf[4][4];
    #pragma unroll
    for (int t = 0; t < 4; ++t)
        #pragma unroll
        for (int s = 0; s < 4; ++s)
            bf[t][s] = *reinterpret_cast<const short8*>(
                &Wt[(16 * t + lrow) * TSTRIDE + 32 * s + 8 * lkg]);

    unsigned short* const op = &ot[wave][0];
    const int orow = lane >> 2;         // 0..15 (readback row)
    const int oseg = lane & 3;          // 0..3  (16-ushort segment)

    auto loadx = [&](float4* xr, int tile) {
        const float* base = x + (size_t)tile * 64 * IN_F
                              + (size_t)(16 * wave + lrow) * IN_F + 8 * lkg;
        #pragma unroll
        for (int s = 0; s < 4; ++s) {
            xr[2 * s]     = *reinterpret_cast<const float4*>(base + 32 * s);
            xr[2 * s + 1] = *reinterpret_cast<const float4*>(base + 32 * s + 4);
        }
    };

    auto process = [&](const float4* xr, int tile) {
        // Convert this lane's A-fragments f32 -> bf16 in-register.
        short8 a[4];
        #pragma unroll
        for (int s = 0; s < 4; ++s) {
            const float* f0 = reinterpret_cast<const float*>(&xr[2 * s]);
            const float* f1 = reinterpret_cast<const float*>(&xr[2 * s + 1]);
            short8 av;
            #pragma unroll
            for (int j = 0; j < 4; ++j) av[j] = (short)f32_to_bf16_rne(f0[j]);
            #pragma unroll
            for (int j = 0; j < 4; ++j) av[4 + j] = (short)f32_to_bf16_rne(f1[j]);
            a[s] = av;
        }

        floatx4 acc[4];
        #pragma unroll
        for (int t = 0; t < 4; ++t) acc[t] = (floatx4){0.f, 0.f, 0.f, 0.f};
        #pragma unroll
        for (int t = 0; t < 4; ++t)
            #pragma unroll
            for (int s = 0; s < 4; ++s)
                acc[t] = __builtin_amdgcn_mfma_f32_16x16x32_bf16(a[s], bf[t][s], acc[t], 0, 0, 0);

        // Stage D (bf16) into this wave's private LDS strip.
        // D layout: row = 4*lkg + r, col = 16*t + lrow.
        #pragma unroll
        for (int t = 0; t < 4; ++t)
            #pragma unroll
            for (int r = 0; r < 4; ++r)
                op[(4 * lkg + r) * OSTRIDE + 16 * t + lrow] = f32_to_bf16_rne(acc[t][r]);

        // Cross-lane readback: explicit fence (compiler's per-lane alias
        // analysis won't order this; rule #18).
        asm volatile("s_waitcnt lgkmcnt(0)" ::: "memory");
        __builtin_amdgcn_sched_barrier(0);

        const short8 o0 = *reinterpret_cast<const short8*>(&op[orow * OSTRIDE + oseg * 16]);
        const short8 o1 = *reinterpret_cast<const short8*>(&op[orow * OSTRIDE + oseg * 16 + 8]);
        unsigned short* hb = h + ((size_t)tile * 64 + 16 * wave + orow) * OUT_F + oseg * 16;
        *reinterpret_cast<short8*>(hb) = o0;
        *reinterpret_cast<short8*>(hb + 8) = o1;
    };

    // 2-deep pipelined persistent loop (named buffers, no runtime indexing).
    int tile = blockIdx.x;
    float4 xa[8], xb[8];
    if (tile < nTiles) loadx(xa, tile);
    while (tile < nTiles) {
        const int t2 = tile + NG;
        if (t2 < nTiles) loadx(xb, t2);
        process(xa, tile);
        tile = t2;
        if (tile >= nTiles) break;
        const int t3 = tile + NG;
        if (t3 < nTiles) loadx(xa, t3);
        process(xb, tile);
        tile = t3;
    }
}

// ---------------------------------------------------------------------------
// Scan chain: per-block scan -> totals scan -> add base.
// ---------------------------------------------------------------------------
__global__ __launch_bounds__(256) void scan_blocks(const int* __restrict__ counts,
                                                   int* __restrict__ offsets,
                                                   int* __restrict__ blockTotals,
                                                   int n) {
    __shared__ int waveTot[4];
    const int tid = threadIdx.x;
    const int lane = tid & 63;
    const int wave = tid >> 6;
    const int i = blockIdx.x * 256 + tid;

    const int v = (i < n) ? counts[i] : 0;

    int s = v;
    #pragma unroll
    for (int off = 1; off < 64; off <<= 1) {
        const int t = __shfl_up(s, off, 64);
        if (lane >= off) s += t;
    }
    if (lane == 63) waveTot[wave] = s;
    __syncthreads();

    int base = 0;
    #pragma unroll
    for (int w = 0; w < 4; ++w)
        if (w < wave) base += waveTot[w];

    const int incl = s + base;
    if (i < n) offsets[i] = incl - v;
    if (tid == 255) blockTotals[blockIdx.x] = incl;
}

__global__ __launch_bounds__(256) void scan_totals(const int* __restrict__ blockTotals,
                                                   int* __restrict__ blockBases,
                                                   int nb) {
    __shared__ int part[256];
    const int t = threadIdx.x;
    const int v = (t < nb) ? blockTotals[t] : 0;
    part[t] = v;
    __syncthreads();
    for (int off = 1; off < 256; off <<= 1) {
        const int u = (t >= off) ? part[t - off] : 0;
        __syncthreads();
        part[t] += u;
        __syncthreads();
    }
    if (t < nb) blockBases[t] = part[t] - v;
}

__global__ __launch_bounds__(256) void add_base(int* __restrict__ offsets,
                                                const int* __restrict__ blockBases,
                                                int n) {
    const int i = blockIdx.x * 256 + threadIdx.x;
    if (i < n) offsets[i] += blockBases[blockIdx.x];
}

// fill bumps offsets (start -> end); gather recovers start via counts.
__global__ __launch_bounds__(256) void fill_edges(const int* __restrict__ esrc,
                                                  const int* __restrict__ edst,
                                                  int* __restrict__ offsets,
                                                  int* __restrict__ elist,
                                                  int n_edges) {
    const int e = blockIdx.x * 256 + threadIdx.x;
    if (e < n_edges) {
        const int d = edst[e];
        const int slot = atomicAdd(&offsets[d], 1);
        elist[slot] = esrc[e];
    }
}

// ---------------------------------------------------------------------------
// K5: gather + finalize. One wave per dst. 4 edges per load instruction:
// lane = 16*eq + p handles cols [4p,4p+4) of edge j+eq (ushort4 = 8 B/lane,
// 512 B/instruction). Final fold across eq-groups via 2x __shfl_xor.
// ---------------------------------------------------------------------------
__global__ __launch_bounds__(256) void gather_finalize(const unsigned short* __restrict__ h,
                                                       const int* __restrict__ offsets,
                                                       const int* __restrict__ counts,
                                                       const int* __restrict__ elist,
                                                       const float* __restrict__ b,
                                                       float* __restrict__ out,
                                                       int n_dst) {
    const int lane = threadIdx.x & 63;
    const int d = blockIdx.x * 4 + (threadIdx.x >> 6);
    if (d >= n_dst) return;

    const int eq = lane >> 4;           // edge slot 0..3
    const int p  = lane & 15;           // col group: cols [4p, 4p+4)

    const int cnt_d = counts[d];
    const int e1 = offsets[d];          // end (post-fill)
    const int e0 = e1 - cnt_d;

    float4 acc = {0.f, 0.f, 0.f, 0.f};

    for (int base = e0; base < e1; base += 64) {
        const int lim = min(64, e1 - base);
        const int sidx = (base + lane < e1) ? elist[base + lane] : 0;
        for (int j = 0; j < lim; j += 4) {
            const int myj = j + eq;
            const bool valid = myj < lim;
            const int s = __shfl(sidx, valid ? myj : 0);
            const ushort4 v = *reinterpret_cast<const ushort4*>(&h[(size_t)s * OUT_F + 4 * p]);
            const float w = valid ? 1.0f : 0.0f;
            acc.x += w * bf16_to_f32(v.x);
            acc.y += w * bf16_to_f32(v.y);
            acc.z += w * bf16_to_f32(v.z);
            acc.w += w * bf16_to_f32(v.w);
        }
    }

    // Fold across the 4 eq-groups (lanes p, p+16, p+32, p+48).
    acc.x += __shfl_xor(acc.x, 32); acc.y += __shfl_xor(acc.y, 32);
    acc.z += __shfl_xor(acc.z, 32); acc.w += __shfl_xor(acc.w, 32);
    acc.x += __shfl_xor(acc.x, 16); acc.y += __shfl_xor(acc.y, 16);
    acc.z += __shfl_xor(acc.z, 16); acc.w += __shfl_xor(acc.w, 16);

    if (lane < 16) {
        const ushort4 hd = *reinterpret_cast<const ushort4*>(&h[(size_t)d * OUT_F + 4 * p]);
        const float4 bb = *reinterpret_cast<const float4*>(&b[4 * p]);
        const float inv = 1.0f / ((float)cnt_d + 1.0f);
        float4 o;
        o.x = (acc.x + bf16_to_f32(hd.x)) * inv + bb.x;
        o.y = (acc.y + bf16_to_f32(hd.y)) * inv + bb.y;
        o.z = (acc.z + bf16_to_f32(hd.z)) * inv + bb.z;
        o.w = (acc.w + bf16_to_f32(hd.w)) * inv + bb.w;
        *reinterpret_cast<float4*>(&out[(size_t)d * OUT_F + 4 * p]) = o;
    }
}

static inline size_t align256(size_t v) { return (v + 255) & ~(size_t)255; }

extern "C" void kernel_launch(void* const* d_in, const int* in_sizes, int n_in,
                              void* d_out, int out_size, void* d_ws, size_t ws_size,
                              hipStream_t stream) {
    const float* x    = (const float*)d_in[0];
    const int*   esrc = (const int*)d_in[1];
    const int*   edst = (const int*)d_in[2];
    const float* W    = (const float*)d_in[3];
    const float* b    = (const float*)d_in[4];

    const int n_rows  = in_sizes[0] / IN_F;   // 200000
    const int n_edges = in_sizes[1];          // 800000
    const int n_dst   = out_size / OUT_F;     // 50000
    float* out = (float*)d_out;

    const int nScanBlocks = (n_dst + 255) / 256;            // 196

    // Workspace layout (h bf16: 25.6 MB)
    const size_t hBytes  = (size_t)n_rows * OUT_F * sizeof(unsigned short);
    const size_t cntOff  = align256(hBytes);
    const size_t offOff  = align256(cntOff + (size_t)n_dst * 4);
    const size_t btOff   = align256(offOff + ((size_t)n_dst + 1) * 4);
    const size_t bbOff   = align256(btOff + ((size_t)nScanBlocks + 1) * 4);
    const size_t elOff   = align256(bbOff + ((size_t)nScanBlocks + 1) * 4);
    const size_t needed  = elOff + (size_t)n_edges * 4;

    unsigned short* h = (unsigned short*)d_ws;

    if (ws_size >= needed) {
        int* counts      = (int*)((char*)d_ws + cntOff);
        int* offsets     = (int*)((char*)d_ws + offOff);
        int* blockTotals = (int*)((char*)d_ws + btOff);
        int* blockBases  = (int*)((char*)d_ws + bbOff);
        int* elist       = (int*)((char*)d_ws + elOff);

        hipMemsetAsync(counts, 0, (size_t)n_dst * 4, stream);

        const int nTiles = n_rows / 64;       // 3125
        gemm_count<<<NG + NC, 256, 0, stream>>>(x, W, h, nTiles, edst, counts, n_edges);

        scan_blocks<<<nScanBlocks, 256, 0, stream>>>(counts, offsets, blockTotals, n_dst);
        scan_totals<<<1, 256, 0, stream>>>(blockTotals, blockBases, nScanBlocks);
        add_base<<<nScanBlocks, 256, 0, stream>>>(offsets, blockBases, n_dst);

        const int eBlocks = (n_edges + 255) / 256;
        fill_edges<<<eBlocks, 256, 0, stream>>>(esrc, edst, offsets, elist, n_edges);

        const int gBlocks = (n_dst + 3) / 4;
        gather_finalize<<<gBlocks, 256, 0, stream>>>(h, offsets, counts, elist, b, out, n_dst);
    } else {
        hipMemsetAsync(out, 0, (size_t)out_size * sizeof(float), stream);
    }
}

// Round 8
// 133.416 us; speedup vs baseline: 1.0294x; 1.0294x over previous
//
#include <hip/hip_runtime.h>
#include <hip/hip_bf16.h>

#define IN_F   128
#define OUT_F  64
#define NG 384              // persistent GEMM blocks
#define NC 128              // edge-count blocks (concurrent); NG+NC = 512 = 2/CU
#define TSTRIDE 136         // W^T LDS stride (ushorts)
#define OSTRIDE 136         // output-stage LDS stride (ushorts, 16B-aligned rows)

typedef __attribute__((ext_vector_type(8))) short short8;   // 8 bf16
typedef __attribute__((ext_vector_type(4))) float floatx4;  // MFMA accumulator

__device__ inline unsigned short f32_to_bf16_rne(float f) {
    unsigned int u = __float_as_uint(f);
    unsigned int r = (u + 0x7FFFu + ((u >> 16) & 1u)) >> 16;
    return (unsigned short)r;
}
__device__ inline float bf16_to_f32(unsigned short u) {
    return __uint_as_float((unsigned int)u << 16);
}

// ---------------------------------------------------------------------------
// K1 (fused): blocks [0,NG) = persistent MFMA GEMM h = x@W (bf16 h out);
// blocks [NG,NG+NC) = count_edges. Co-resident (2 blocks/CU).
// GEMM: NO LDS in the K-loop; W-frags in 64 VGPRs; A-frags straight from
// global; 2-deep tile pipeline. Working set ~180 VGPR -> REQUIRES
// __launch_bounds__(256, 1): bare (256) capped alloc at 96 VGPR and
// spilled ~25 MB/dispatch to scratch (r7: WRITE 50 MB, 95% stall).
// ---------------------------------------------------------------------------
__global__ __launch_bounds__(256, 1) void gemm_count(const float* __restrict__ x,
                                                     const float* __restrict__ W,
                                                     unsigned short* __restrict__ h,
                                                     int nTiles,
                                                     const int* __restrict__ edst,
                                                     int* __restrict__ counts,
                                                     int n_edges) {
    __shared__ unsigned short Wt[64 * TSTRIDE];      // 17.4 KB
    __shared__ unsigned short ot[4][16 * OSTRIDE];   // 17.4 KB (per-wave strips)

    const int tid = threadIdx.x;

    if (blockIdx.x >= NG) {
        // --- count role ---
        const int stride = NC * 256;
        for (int e = (blockIdx.x - NG) * 256 + tid; e < n_edges; e += stride)
            atomicAdd(&counts[edst[e]], 1);
        return;
    }

    // --- GEMM role ---
    const int lane = tid & 63;
    const int wave = tid >> 6;          // 0..3 -> rows [16*wave, 16*wave+16)
    const int lrow = lane & 15;
    const int lkg  = lane >> 4;         // k-group; k offset = 8*lkg

    // One-time: W (128x64 f32) -> Wt[col][k] bf16 in LDS.
    #pragma unroll
    for (int i = 0; i < 32; ++i) {
        const int idx = tid + i * 256;          // 0..8191
        Wt[(idx & 63) * TSTRIDE + (idx >> 6)] = f32_to_bf16_rne(W[idx]);
    }
    __syncthreads();

    // Hoist all 16 B-fragments into registers (read LDS exactly once).
    // B-frag (m89 layout): element j = W[kbase + 8*lkg + j][16*t + lrow].
    short8 bf[4][4];
    #pragma unroll
    for (int t = 0; t < 4; ++t)
        #pragma unroll
        for (int s = 0; s < 4; ++s)
            bf[t][s] = *reinterpret_cast<const short8*>(
                &Wt[(16 * t + lrow) * TSTRIDE + 32 * s + 8 * lkg]);

    unsigned short* const op = &ot[wave][0];
    const int orow = lane >> 2;         // 0..15 (readback row)
    const int oseg = lane & 3;          // 0..3  (16-ushort segment)

    auto loadx = [&](float4* xr, int tile) {
        const float* base = x + (size_t)tile * 64 * IN_F
                              + (size_t)(16 * wave + lrow) * IN_F + 8 * lkg;
        #pragma unroll
        for (int s = 0; s < 4; ++s) {
            xr[2 * s]     = *reinterpret_cast<const float4*>(base + 32 * s);
            xr[2 * s + 1] = *reinterpret_cast<const float4*>(base + 32 * s + 4);
        }
    };

    auto process = [&](const float4* xr, int tile) {
        // Convert this lane's A-fragments f32 -> bf16 in-register.
        short8 a[4];
        #pragma unroll
        for (int s = 0; s < 4; ++s) {
            const float* f0 = reinterpret_cast<const float*>(&xr[2 * s]);
            const float* f1 = reinterpret_cast<const float*>(&xr[2 * s + 1]);
            short8 av;
            #pragma unroll
            for (int j = 0; j < 4; ++j) av[j] = (short)f32_to_bf16_rne(f0[j]);
            #pragma unroll
            for (int j = 0; j < 4; ++j) av[4 + j] = (short)f32_to_bf16_rne(f1[j]);
            a[s] = av;
        }

        floatx4 acc[4];
        #pragma unroll
        for (int t = 0; t < 4; ++t) acc[t] = (floatx4){0.f, 0.f, 0.f, 0.f};
        #pragma unroll
        for (int t = 0; t < 4; ++t)
            #pragma unroll
            for (int s = 0; s < 4; ++s)
                acc[t] = __builtin_amdgcn_mfma_f32_16x16x32_bf16(a[s], bf[t][s], acc[t], 0, 0, 0);

        // Stage D (bf16) into this wave's private LDS strip.
        // D layout: row = 4*lkg + r, col = 16*t + lrow.
        #pragma unroll
        for (int t = 0; t < 4; ++t)
            #pragma unroll
            for (int r = 0; r < 4; ++r)
                op[(4 * lkg + r) * OSTRIDE + 16 * t + lrow] = f32_to_bf16_rne(acc[t][r]);

        // Cross-lane readback: explicit fence (rule #18).
        asm volatile("s_waitcnt lgkmcnt(0)" ::: "memory");
        __builtin_amdgcn_sched_barrier(0);

        const short8 o0 = *reinterpret_cast<const short8*>(&op[orow * OSTRIDE + oseg * 16]);
        const short8 o1 = *reinterpret_cast<const short8*>(&op[orow * OSTRIDE + oseg * 16 + 8]);
        unsigned short* hb = h + ((size_t)tile * 64 + 16 * wave + orow) * OUT_F + oseg * 16;
        *reinterpret_cast<short8*>(hb) = o0;
        *reinterpret_cast<short8*>(hb + 8) = o1;
    };

    // 2-deep pipelined persistent loop (named buffers, no runtime indexing).
    int tile = blockIdx.x;
    float4 xa[8], xb[8];
    if (tile < nTiles) loadx(xa, tile);
    while (tile < nTiles) {
        const int t2 = tile + NG;
        if (t2 < nTiles) loadx(xb, t2);
        process(xa, tile);
        tile = t2;
        if (tile >= nTiles) break;
        const int t3 = tile + NG;
        if (t3 < nTiles) loadx(xa, t3);
        process(xb, tile);
        tile = t3;
    }
}

// ---------------------------------------------------------------------------
// Scan chain: per-block scan -> totals scan -> add base.
// ---------------------------------------------------------------------------
__global__ __launch_bounds__(256) void scan_blocks(const int* __restrict__ counts,
                                                   int* __restrict__ offsets,
                                                   int* __restrict__ blockTotals,
                                                   int n) {
    __shared__ int waveTot[4];
    const int tid = threadIdx.x;
    const int lane = tid & 63;
    const int wave = tid >> 6;
    const int i = blockIdx.x * 256 + tid;

    const int v = (i < n) ? counts[i] : 0;

    int s = v;
    #pragma unroll
    for (int off = 1; off < 64; off <<= 1) {
        const int t = __shfl_up(s, off, 64);
        if (lane >= off) s += t;
    }
    if (lane == 63) waveTot[wave] = s;
    __syncthreads();

    int base = 0;
    #pragma unroll
    for (int w = 0; w < 4; ++w)
        if (w < wave) base += waveTot[w];

    const int incl = s + base;
    if (i < n) offsets[i] = incl - v;
    if (tid == 255) blockTotals[blockIdx.x] = incl;
}

__global__ __launch_bounds__(256) void scan_totals(const int* __restrict__ blockTotals,
                                                   int* __restrict__ blockBases,
                                                   int nb) {
    __shared__ int part[256];
    const int t = threadIdx.x;
    const int v = (t < nb) ? blockTotals[t] : 0;
    part[t] = v;
    __syncthreads();
    for (int off = 1; off < 256; off <<= 1) {
        const int u = (t >= off) ? part[t - off] : 0;
        __syncthreads();
        part[t] += u;
        __syncthreads();
    }
    if (t < nb) blockBases[t] = part[t] - v;
}

__global__ __launch_bounds__(256) void add_base(int* __restrict__ offsets,
                                                const int* __restrict__ blockBases,
                                                int n) {
    const int i = blockIdx.x * 256 + threadIdx.x;
    if (i < n) offsets[i] += blockBases[blockIdx.x];
}

// fill bumps offsets (start -> end); gather recovers start via counts.
__global__ __launch_bounds__(256) void fill_edges(const int* __restrict__ esrc,
                                                  const int* __restrict__ edst,
                                                  int* __restrict__ offsets,
                                                  int* __restrict__ elist,
                                                  int n_edges) {
    const int e = blockIdx.x * 256 + threadIdx.x;
    if (e < n_edges) {
        const int d = edst[e];
        const int slot = atomicAdd(&offsets[d], 1);
        elist[slot] = esrc[e];
    }
}

// ---------------------------------------------------------------------------
// K5: gather + finalize. One wave per dst. 4 edges per load instruction:
// lane = 16*eq + p handles cols [4p,4p+4) of edge j+eq (ushort4 = 8 B/lane,
// 512 B/instruction). Final fold across eq-groups via 2x __shfl_xor.
// ---------------------------------------------------------------------------
__global__ __launch_bounds__(256) void gather_finalize(const unsigned short* __restrict__ h,
                                                       const int* __restrict__ offsets,
                                                       const int* __restrict__ counts,
                                                       const int* __restrict__ elist,
                                                       const float* __restrict__ b,
                                                       float* __restrict__ out,
                                                       int n_dst) {
    const int lane = threadIdx.x & 63;
    const int d = blockIdx.x * 4 + (threadIdx.x >> 6);
    if (d >= n_dst) return;

    const int eq = lane >> 4;           // edge slot 0..3
    const int p  = lane & 15;           // col group: cols [4p, 4p+4)

    const int cnt_d = counts[d];
    const int e1 = offsets[d];          // end (post-fill)
    const int e0 = e1 - cnt_d;

    float4 acc = {0.f, 0.f, 0.f, 0.f};

    for (int base = e0; base < e1; base += 64) {
        const int lim = min(64, e1 - base);
        const int sidx = (base + lane < e1) ? elist[base + lane] : 0;
        for (int j = 0; j < lim; j += 4) {
            const int myj = j + eq;
            const bool valid = myj < lim;
            const int s = __shfl(sidx, valid ? myj : 0);
            const ushort4 v = *reinterpret_cast<const ushort4*>(&h[(size_t)s * OUT_F + 4 * p]);
            const float w = valid ? 1.0f : 0.0f;
            acc.x += w * bf16_to_f32(v.x);
            acc.y += w * bf16_to_f32(v.y);
            acc.z += w * bf16_to_f32(v.z);
            acc.w += w * bf16_to_f32(v.w);
        }
    }

    // Fold across the 4 eq-groups (lanes p, p+16, p+32, p+48).
    acc.x += __shfl_xor(acc.x, 32); acc.y += __shfl_xor(acc.y, 32);
    acc.z += __shfl_xor(acc.z, 32); acc.w += __shfl_xor(acc.w, 32);
    acc.x += __shfl_xor(acc.x, 16); acc.y += __shfl_xor(acc.y, 16);
    acc.z += __shfl_xor(acc.z, 16); acc.w += __shfl_xor(acc.w, 16);

    if (lane < 16) {
        const ushort4 hd = *reinterpret_cast<const ushort4*>(&h[(size_t)d * OUT_F + 4 * p]);
        const float4 bb = *reinterpret_cast<const float4*>(&b[4 * p]);
        const float inv = 1.0f / ((float)cnt_d + 1.0f);
        float4 o;
        o.x = (acc.x + bf16_to_f32(hd.x)) * inv + bb.x;
        o.y = (acc.y + bf16_to_f32(hd.y)) * inv + bb.y;
        o.z = (acc.z + bf16_to_f32(hd.z)) * inv + bb.z;
        o.w = (acc.w + bf16_to_f32(hd.w)) * inv + bb.w;
        *reinterpret_cast<float4*>(&out[(size_t)d * OUT_F + 4 * p]) = o;
    }
}

static inline size_t align256(size_t v) { return (v + 255) & ~(size_t)255; }

extern "C" void kernel_launch(void* const* d_in, const int* in_sizes, int n_in,
                              void* d_out, int out_size, void* d_ws, size_t ws_size,
                              hipStream_t stream) {
    const float* x    = (const float*)d_in[0];
    const int*   esrc = (const int*)d_in[1];
    const int*   edst = (const int*)d_in[2];
    const float* W    = (const float*)d_in[3];
    const float* b    = (const float*)d_in[4];

    const int n_rows  = in_sizes[0] / IN_F;   // 200000
    const int n_edges = in_sizes[1];          // 800000
    const int n_dst   = out_size / OUT_F;     // 50000
    float* out = (float*)d_out;

    const int nScanBlocks = (n_dst + 255) / 256;            // 196

    // Workspace layout (h bf16: 25.6 MB)
    const size_t hBytes  = (size_t)n_rows * OUT_F * sizeof(unsigned short);
    const size_t cntOff  = align256(hBytes);
    const size_t offOff  = align256(cntOff + (size_t)n_dst * 4);
    const size_t btOff   = align256(offOff + ((size_t)n_dst + 1) * 4);
    const size_t bbOff   = align256(btOff + ((size_t)nScanBlocks + 1) * 4);
    const size_t elOff   = align256(bbOff + ((size_t)nScanBlocks + 1) * 4);
    const size_t needed  = elOff + (size_t)n_edges * 4;

    unsigned short* h = (unsigned short*)d_ws;

    if (ws_size >= needed) {
        int* counts      = (int*)((char*)d_ws + cntOff);
        int* offsets     = (int*)((char*)d_ws + offOff);
        int* blockTotals = (int*)((char*)d_ws + btOff);
        int* blockBases  = (int*)((char*)d_ws + bbOff);
        int* elist       = (int*)((char*)d_ws + elOff);

        hipMemsetAsync(counts, 0, (size_t)n_dst * 4, stream);

        const int nTiles = n_rows / 64;       // 3125
        gemm_count<<<NG + NC, 256, 0, stream>>>(x, W, h, nTiles, edst, counts, n_edges);

        scan_blocks<<<nScanBlocks, 256, 0, stream>>>(counts, offsets, blockTotals, n_dst);
        scan_totals<<<1, 256, 0, stream>>>(blockTotals, blockBases, nScanBlocks);
        add_base<<<nScanBlocks, 256, 0, stream>>>(offsets, blockBases, n_dst);

        const int eBlocks = (n_edges + 255) / 256;
        fill_edges<<<eBlocks, 256, 0, stream>>>(esrc, edst, offsets, elist, n_edges);

        const int gBlocks = (n_dst + 3) / 4;
        gather_finalize<<<gBlocks, 256, 0, stream>>>(h, offsets, counts, elist, b, out, n_dst);
    } else {
        hipMemsetAsync(out, 0, (size_t)out_size * sizeof(float), stream);
    }
}